// Round 5
// baseline (166.078 us; speedup 1.0000x reference)
//
#include <hip/hip_runtime.h>
#include <hip/hip_bf16.h>

// Problem constants (fixed by reference setup_inputs)
#define BROWS 4096
#define NE    16
#define HDIM  1024
// ws floats: [0..15] usage, [16] ent, [17] eff, [18..49] kl, [50..81] cnt, [82] ticket
#define ACC_F 128
#define NTILE 32                              // 4096 / 128
#define NBLK  (NTILE * (NTILE + 1) / 2)       // 528 upper-triangular block pairs

typedef __attribute__((ext_vector_type(8))) short short8;   // 8 bf16 (4 VGPRs)
typedef __attribute__((ext_vector_type(4))) float float4v;  // 4 f32

// f32 -> bf16 round-to-nearest-even, low 16 bits
__device__ __forceinline__ unsigned bf16rne(float f) {
    const unsigned u = __float_as_uint(f);
    return (u + 0x7FFFu + ((u >> 16) & 1u)) >> 16;
}
__device__ __forceinline__ unsigned pk2(float lo, float hi) {
    return bf16rne(lo) | (bf16rne(hi) << 16);
}

__device__ __forceinline__ void row16f(const float* src, float* p) {
    const float4v* pv = (const float4v*)src;
    float4v a0 = pv[0], a1 = pv[1], a2 = pv[2], a3 = pv[3];
    p[0]=a0.x; p[1]=a0.y; p[2]=a0.z; p[3]=a0.w;
    p[4]=a1.x; p[5]=a1.y; p[6]=a1.z; p[7]=a1.w;
    p[8]=a2.x; p[9]=a2.y; p[10]=a2.z; p[11]=a2.w;
    p[12]=a3.x; p[13]=a3.y; p[14]=a3.z; p[15]=a3.w;
}

// log_softmax of a 16-vector
__device__ __forceinline__ void lsm16(const float* p, float* lp, float* q, float& ne) {
    float m = p[0];
#pragma unroll
    for (int e = 1; e < 16; e++) m = fmaxf(m, p[e]);
    float s = 0.f;
#pragma unroll
    for (int e = 0; e < 16; e++) s += expf(p[e] - m);
    const float ls = logf(s);
    ne = 0.f;
#pragma unroll
    for (int e = 0; e < 16; e++) {
        lp[e] = p[e] - m - ls;
        q[e]  = expf(lp[e]);
        ne   += q[e] * lp[e];
    }
}

// read a stride-20 LDS row (16 floats)
__device__ __forceinline__ void ldsrow16(const float* base, float* r) {
    float4v a0 = *(const float4v*)(base);
    float4v a1 = *(const float4v*)(base + 4);
    float4v a2 = *(const float4v*)(base + 8);
    float4v a3 = *(const float4v*)(base + 12);
    r[0]=a0.x; r[1]=a0.y; r[2]=a0.z; r[3]=a0.w;
    r[4]=a1.x; r[5]=a1.y; r[6]=a1.z; r[7]=a1.w;
    r[8]=a2.x; r[9]=a2.y; r[10]=a2.z; r[11]=a2.w;
    r[12]=a3.x; r[13]=a3.y; r[14]=a3.z; r[15]=a3.w;
}

// ---------------- convert emb f32 -> bf16; block 0 also zeroes accumulators ----------------
__global__ __launch_bounds__(256) void conv_init(
    const float* __restrict__ src, unsigned short* __restrict__ dst, float* __restrict__ acc)
{
    if (blockIdx.x == 0 && threadIdx.x < ACC_F) acc[threadIdx.x] = 0.f;
    const size_t i = ((size_t)blockIdx.x * 256 + threadIdx.x) * 8;
    float4v a = *(const float4v*)(src + i);
    float4v b = *(const float4v*)(src + i + 4);
    uint4 w = {pk2(a.x,a.y), pk2(a.z,a.w), pk2(b.x,b.y), pk2(b.z,b.w)};
    *(uint4*)(dst + i) = w;
}

// ---------------- Kernel B: symmetric Gram GEMM + masked bidirectional KL + finalize ----------------
// Upper-triangular block pairs (bi<=bj). mask = (dot>0)&&(i!=j) (norms positive).
// Forward: kl[i,j] = ne_j - lp_i.q_j. Off-diag also reverse: kl[j,i] = ne_i - lp_j.q_i.
// Diagonal blocks fold usage/entropy/efficiency row stats. Last-finished block finalizes.
template<bool PRE>
__global__ __launch_bounds__(256) void gram_kl(
    const float* __restrict__ embf, const unsigned short* __restrict__ embb,
    const float* __restrict__ rp, float* __restrict__ acc,
    unsigned int* __restrict__ out)
{
    __shared__ char smem[40960];
    __shared__ float red[8];
    __shared__ int islast;
    __shared__ float fin[96];
    // K-loop view (16 KB):
    __hip_bfloat16* tA = (__hip_bfloat16*)smem;            // [128][32] bf16, chunk-swizzled
    __hip_bfloat16* tB = (__hip_bfloat16*)(smem + 8192);
    // epilogue view (40 KB, reused): rows stride 20 f32, [16] = ne
    float* lpI = (float*)smem;
    float* qI  = (float*)(smem + 10240);
    float* lpJ = (float*)(smem + 20480);
    float* qJ  = (float*)(smem + 30720);

    // triangular decode: id = bj*(bj+1)/2 + bi, bi <= bj
    const int id = blockIdx.x;
    int r = (int)((sqrtf(8.f * (float)id + 1.f) - 1.f) * 0.5f);
    while ((r + 1) * (r + 2) / 2 <= id) r++;
    while (r * (r + 1) / 2 > id) r--;
    const int bj = r, bi = id - r * (r + 1) / 2;

    const int t = threadIdx.x;
    const int lane = t & 63, wid = t >> 6;
    const int wi0 = (wid >> 1) * 64, wj0 = (wid & 1) * 64;
    const int lrow = lane & 15, quad = lane >> 4;

    // staging: thread t covers rows {t>>2, 64+(t>>2)}, 16B chunk cp (XOR-swizzled placement)
    const int row0 = t >> 2, cp = t & 3;
    const int row1 = 64 + row0;
    const int sw0 = cp ^ ((row0 >> 1) & 3);      // (row1>>1)&3 == (row0>>1)&3 + 32 ≡ same &3
    // swizzled LDS offsets (bf16 units)
    const int oA0 = row0 * 32 + sw0 * 8, oA1 = row1 * 32 + sw0 * 8;

    float4v accf[4][4];
#pragma unroll
    for (int a = 0; a < 4; a++)
#pragma unroll
        for (int b = 0; b < 4; b++) { accf[a][b].x=0.f; accf[a][b].y=0.f; accf[a][b].z=0.f; accf[a][b].w=0.f; }

    // fragment read offsets (swizzle depends only on row)
    int roA[4], roB[4];
#pragma unroll
    for (int f = 0; f < 4; f++) {
        const int ra = wi0 + f * 16 + lrow;
        const int rb = wj0 + f * 16 + lrow;
        roA[f] = ra * 32 + (quad ^ ((ra >> 1) & 3)) * 8;
        roB[f] = rb * 32 + (quad ^ ((rb >> 1) & 3)) * 8;
    }

    if (PRE) {
        const unsigned short* gA = embb + (size_t)(bi * 128) * HDIM;
        const unsigned short* gB = embb + (size_t)(bj * 128) * HDIM;
        // preload kt=0
        uint4 va0 = *(const uint4*)(gA + (size_t)row0 * HDIM + cp * 8);
        uint4 va1 = *(const uint4*)(gA + (size_t)row1 * HDIM + cp * 8);
        uint4 vb0 = *(const uint4*)(gB + (size_t)row0 * HDIM + cp * 8);
        uint4 vb1 = *(const uint4*)(gB + (size_t)row1 * HDIM + cp * 8);
        for (int kt = 0; kt < HDIM; kt += 32) {
            __syncthreads();                 // prev iter's fragment reads done
            *(uint4*)(tA + oA0) = va0;
            *(uint4*)(tA + oA1) = va1;
            *(uint4*)(tB + oA0) = vb0;
            *(uint4*)(tB + oA1) = vb1;
            __syncthreads();
            const int kn = (kt + 32 < HDIM) ? (kt + 32) : kt;   // uniform; last reload harmless
            va0 = *(const uint4*)(gA + (size_t)row0 * HDIM + kn + cp * 8);
            va1 = *(const uint4*)(gA + (size_t)row1 * HDIM + kn + cp * 8);
            vb0 = *(const uint4*)(gB + (size_t)row0 * HDIM + kn + cp * 8);
            vb1 = *(const uint4*)(gB + (size_t)row1 * HDIM + kn + cp * 8);
            short8 a[4], b[4];
#pragma unroll
            for (int f = 0; f < 4; f++) {
                a[f] = *(const short8*)(tA + roA[f]);
                b[f] = *(const short8*)(tB + roB[f]);
            }
#pragma unroll
            for (int fi = 0; fi < 4; fi++)
#pragma unroll
                for (int fj = 0; fj < 4; fj++)
                    accf[fi][fj] = __builtin_amdgcn_mfma_f32_16x16x32_bf16(
                        a[fi], b[fj], accf[fi][fj], 0, 0, 0);
        }
    } else {
        // fallback (ws too small): in-loop f32->bf16 conversion, same pipeline
        const float* gA = embf + (size_t)(bi * 128) * HDIM;
        const float* gB = embf + (size_t)(bj * 128) * HDIM;
        float4v a00,a01,a10,a11,b00,b01,b10,b11;
        {
            const float* pa0 = gA + (size_t)row0 * HDIM + cp * 8;
            const float* pa1 = gA + (size_t)row1 * HDIM + cp * 8;
            const float* pb0 = gB + (size_t)row0 * HDIM + cp * 8;
            const float* pb1 = gB + (size_t)row1 * HDIM + cp * 8;
            a00=*(const float4v*)pa0; a01=*(const float4v*)(pa0+4);
            a10=*(const float4v*)pa1; a11=*(const float4v*)(pa1+4);
            b00=*(const float4v*)pb0; b01=*(const float4v*)(pb0+4);
            b10=*(const float4v*)pb1; b11=*(const float4v*)(pb1+4);
        }
        for (int kt = 0; kt < HDIM; kt += 32) {
            uint4 wa0 = {pk2(a00.x,a00.y), pk2(a00.z,a00.w), pk2(a01.x,a01.y), pk2(a01.z,a01.w)};
            uint4 wa1 = {pk2(a10.x,a10.y), pk2(a10.z,a10.w), pk2(a11.x,a11.y), pk2(a11.z,a11.w)};
            uint4 wb0 = {pk2(b00.x,b00.y), pk2(b00.z,b00.w), pk2(b01.x,b01.y), pk2(b01.z,b01.w)};
            uint4 wb1 = {pk2(b10.x,b10.y), pk2(b10.z,b10.w), pk2(b11.x,b11.y), pk2(b11.z,b11.w)};
            __syncthreads();
            *(uint4*)(tA + oA0) = wa0;
            *(uint4*)(tA + oA1) = wa1;
            *(uint4*)(tB + oA0) = wb0;
            *(uint4*)(tB + oA1) = wb1;
            __syncthreads();
            const int kn = (kt + 32 < HDIM) ? (kt + 32) : kt;
            const float* pa0 = gA + (size_t)row0 * HDIM + kn + cp * 8;
            const float* pa1 = gA + (size_t)row1 * HDIM + kn + cp * 8;
            const float* pb0 = gB + (size_t)row0 * HDIM + kn + cp * 8;
            const float* pb1 = gB + (size_t)row1 * HDIM + kn + cp * 8;
            a00=*(const float4v*)pa0; a01=*(const float4v*)(pa0+4);
            a10=*(const float4v*)pa1; a11=*(const float4v*)(pa1+4);
            b00=*(const float4v*)pb0; b01=*(const float4v*)(pb0+4);
            b10=*(const float4v*)pb1; b11=*(const float4v*)(pb1+4);
            short8 a[4], b[4];
#pragma unroll
            for (int f = 0; f < 4; f++) {
                a[f] = *(const short8*)(tA + roA[f]);
                b[f] = *(const short8*)(tB + roB[f]);
            }
#pragma unroll
            for (int fi = 0; fi < 4; fi++)
#pragma unroll
                for (int fj = 0; fj < 4; fj++)
                    accf[fi][fj] = __builtin_amdgcn_mfma_f32_16x16x32_bf16(
                        a[fi], b[fj], accf[fi][fj], 0, 0, 0);
        }
    }
    __syncthreads();  // K-loop LDS reads done before epilogue overwrites smem

    // ---- epilogue staging: waves 0,1 -> I rows; waves 2,3 -> J rows ----
    {
        float p[16], lp[16], q[16], ne;
        const bool iSide = (t < 128);
        const int rloc = iSide ? t : (t - 128);
        const int grow = (iSide ? bi : bj) * 128 + rloc;
        row16f(rp + (size_t)grow * NE, p);
        lsm16(p, lp, q, ne);
        float* dl = (iSide ? lpI : lpJ) + rloc * 20;
        float* dq = (iSide ? qI  : qJ ) + rloc * 20;
        float4v l0 = {lp[0],lp[1],lp[2],lp[3]},   l1 = {lp[4],lp[5],lp[6],lp[7]};
        float4v l2 = {lp[8],lp[9],lp[10],lp[11]}, l3 = {lp[12],lp[13],lp[14],lp[15]};
        *(float4v*)dl = l0; *(float4v*)(dl+4) = l1; *(float4v*)(dl+8) = l2; *(float4v*)(dl+12) = l3;
        float4v q0 = {q[0],q[1],q[2],q[3]},   q1 = {q[4],q[5],q[6],q[7]};
        float4v q2 = {q[8],q[9],q[10],q[11]}, q3 = {q[12],q[13],q[14],q[15]};
        *(float4v*)dq = q0; *(float4v*)(dq+4) = q1; *(float4v*)(dq+8) = q2; *(float4v*)(dq+12) = q3;
        dq[16] = ne;

        if (bi == bj && iSide) {   // fold row stats (each row in exactly one diag block's I side)
            float ent = 0.f, eff = 0.f;
#pragma unroll
            for (int e = 0; e < 16; e++) {
                ent += p[e] * logf(p[e] + 1e-8f);
                if (p[e] < 0.1f) eff += p[e];
            }
#pragma unroll
            for (int e = 0; e < 18; e++) {
                float v = (e < 16) ? p[e] : ((e == 16) ? ent : eff);
#pragma unroll
                for (int off = 32; off > 0; off >>= 1) v += __shfl_down(v, off);
                if (lane == 0) atomicAdd(&acc[e], v);
            }
        }
    }
    __syncthreads();

    float klacc = 0.f, cntacc = 0.f;

    // ---- forward: kl[i,j] = ne_j - lp_i.q_j  (C layout: col=lane&15, row=quad*4+reg)
    {
        float qreg[4][16], nereg[4];
        int jg[4];
#pragma unroll
        for (int fj = 0; fj < 4; fj++) {
            const int jc = wj0 + fj * 16 + lrow;
            ldsrow16(qJ + jc * 20, qreg[fj]);
            nereg[fj] = qJ[jc * 20 + 16];
            jg[fj] = bj * 128 + jc;
        }
#pragma unroll
        for (int fi = 0; fi < 4; fi++) {
#pragma unroll
            for (int rg = 0; rg < 4; rg++) {
                const int rr = wi0 + fi * 16 + quad * 4 + rg;
                float lpr[16];
                ldsrow16(lpI + rr * 20, lpr);
                const int ig = bi * 128 + rr;
#pragma unroll
                for (int fj = 0; fj < 4; fj++) {
                    float d = 0.f;
#pragma unroll
                    for (int e = 0; e < 16; e++) d += lpr[e] * qreg[fj][e];
                    const float g = accf[fi][fj][rg];
                    if ((g > 0.f) && (ig != jg[fj])) { klacc += nereg[fj] - d; cntacc += 1.f; }
                }
            }
        }
    }

    // ---- reverse (off-diagonal only): kl[j,i] = ne_i - lp_j.q_i
    if (bi != bj) {
        float lpjr[4][16];
#pragma unroll
        for (int fj = 0; fj < 4; fj++) {
            const int jc = wj0 + fj * 16 + lrow;
            ldsrow16(lpJ + jc * 20, lpjr[fj]);
        }
#pragma unroll
        for (int fi = 0; fi < 4; fi++) {
#pragma unroll
            for (int rg = 0; rg < 4; rg++) {
                const int rr = wi0 + fi * 16 + quad * 4 + rg;
                float qrow[16];
                ldsrow16(qI + rr * 20, qrow);
                const float nei = qI[rr * 20 + 16];
#pragma unroll
                for (int fj = 0; fj < 4; fj++) {
                    float d = 0.f;
#pragma unroll
                    for (int e = 0; e < 16; e++) d += lpjr[fj][e] * qrow[e];
                    const float g = accf[fi][fj][rg];
                    if (g > 0.f) { klacc += nei - d; cntacc += 1.f; }
                }
            }
        }
    }

    // block reduce -> striped atomics
#pragma unroll
    for (int off = 32; off > 0; off >>= 1) {
        klacc  += __shfl_down(klacc, off);
        cntacc += __shfl_down(cntacc, off);
    }
    if (lane == 0) { red[wid] = klacc; red[4 + wid] = cntacc; }
    __syncthreads();
    if (t == 0) {
        atomicAdd(&acc[18 + (id & 31)], red[0] + red[1] + red[2] + red[3]);
        atomicAdd(&acc[50 + (id & 31)], red[4] + red[5] + red[6] + red[7]);
    }

    // ---- last-finished block finalizes (device-scope ticket) ----
    __threadfence();
    if (t == 0) {
        const unsigned got = atomicAdd((unsigned int*)(acc + 82), 1u);
        islast = (got == NBLK - 1) ? 1 : 0;
    }
    __syncthreads();
    if (islast) {
        if (t < 82) fin[t] = atomicAdd(&acc[t], 0.f);   // device-scope coherent read
        __syncthreads();
        if (t == 0) {
            float u[16], usum = 0.f;
#pragma unroll
            for (int e = 0; e < 16; e++) { u[e] = fin[e] / (float)BROWS; usum += u[e]; }
            const float mean = usum / 16.f;
            float var = 0.f;
#pragma unroll
            for (int e = 0; e < 16; e++) { float dd = u[e] - mean; var += dd * dd; }
            var /= 15.f;
            const float lb  = var * 256.f;
            const float ent = fin[16] / (float)BROWS;
            const float eff = fin[17] / (float)BROWS;
            float kl = 0.f, cnt = 0.f;
#pragma unroll
            for (int s = 0; s < 32; s++) { kl += fin[18 + s]; cnt += fin[50 + s]; }
            const float cons = (cnt > 0.f) ? (kl / fmaxf(cnt, 1.f)) : 0.f;
            const float total = lb + ent + eff + cons;
            // low16 = exact bf16(total); full word ~ f32(total) (rel err < 2^-9)
            const unsigned fb   = __float_as_uint(total);
            const unsigned hi   = fb >> 16;
            const unsigned mant = fb & 0xFFFFu;
            const unsigned rnd  = (mant > 0x8000u || (mant == 0x8000u && (hi & 1))) ? 1u : 0u;
            out[0] = (fb & 0xFFFF0000u) | ((hi + rnd) & 0xFFFFu);
        }
    }
}

extern "C" void kernel_launch(void* const* d_in, const int* in_sizes, int n_in,
                              void* d_out, int out_size, void* d_ws, size_t ws_size,
                              hipStream_t stream) {
    const float* rp  = (const float*)d_in[0];   // [4096,16]   f32
    const float* emb = (const float*)d_in[1];   // [4096,1024] f32
    float* acc = (float*)d_ws;
    unsigned short* embb = (unsigned short*)((char*)d_ws + ACC_F * sizeof(float));
    (void)in_sizes; (void)n_in; (void)out_size;

    const size_t need = ACC_F * sizeof(float) + (size_t)BROWS * HDIM * 2;
    const bool pre = (ws_size >= need);   // constant across calls -> capture-safe

    if (pre) {
        conv_init<<<(BROWS * HDIM) / (256 * 8), 256, 0, stream>>>(emb, embb, acc);
        gram_kl<true><<<NBLK, 256, 0, stream>>>(emb, embb, rp, acc, (unsigned int*)d_out);
    } else {
        conv_init<<<1, 256, 0, stream>>>(emb, embb, acc);  // still zeroes acc (block 0)
        gram_kl<false><<<NBLK, 256, 0, stream>>>(emb, (const unsigned short*)nullptr, rp, acc,
                                                 (unsigned int*)d_out);
    }
}

// Round 6
// 136.845 us; speedup vs baseline: 1.2136x; 1.2136x over previous
//
#include <hip/hip_runtime.h>
#include <hip/hip_bf16.h>

// Problem constants (fixed by reference setup_inputs)
#define BROWS 4096
#define NE    16
#define HDIM  1024
// ws floats: [0..15] usage, [16] ent, [17] eff, [18..49] kl, [50..81] cnt, [82] ticket
#define ACC_F 128
#define NTILE 32                              // 4096 / 128
#define NBLK  (NTILE * (NTILE + 1) / 2)       // 528 upper-triangular block pairs

typedef __attribute__((ext_vector_type(8))) short short8;   // 8 bf16 (4 VGPRs)
typedef __attribute__((ext_vector_type(4))) float float4v;  // 4 f32

// f32 -> bf16 round-to-nearest-even, low 16 bits
__device__ __forceinline__ unsigned bf16rne(float f) {
    const unsigned u = __float_as_uint(f);
    return (u + 0x7FFFu + ((u >> 16) & 1u)) >> 16;
}
__device__ __forceinline__ unsigned pk2(float lo, float hi) {
    return bf16rne(lo) | (bf16rne(hi) << 16);
}

__device__ __forceinline__ void row16f(const float* src, float* p) {
    const float4v* pv = (const float4v*)src;
    float4v a0 = pv[0], a1 = pv[1], a2 = pv[2], a3 = pv[3];
    p[0]=a0.x; p[1]=a0.y; p[2]=a0.z; p[3]=a0.w;
    p[4]=a1.x; p[5]=a1.y; p[6]=a1.z; p[7]=a1.w;
    p[8]=a2.x; p[9]=a2.y; p[10]=a2.z; p[11]=a2.w;
    p[12]=a3.x; p[13]=a3.y; p[14]=a3.z; p[15]=a3.w;
}

// log_softmax of a 16-vector
__device__ __forceinline__ void lsm16(const float* p, float* lp, float* q, float& ne) {
    float m = p[0];
#pragma unroll
    for (int e = 1; e < 16; e++) m = fmaxf(m, p[e]);
    float s = 0.f;
#pragma unroll
    for (int e = 0; e < 16; e++) s += expf(p[e] - m);
    const float ls = logf(s);
    ne = 0.f;
#pragma unroll
    for (int e = 0; e < 16; e++) {
        lp[e] = p[e] - m - ls;
        q[e]  = expf(lp[e]);
        ne   += q[e] * lp[e];
    }
}

// read a stride-20 LDS row (16 floats)
__device__ __forceinline__ void ldsrow16(const float* base, float* r) {
    float4v a0 = *(const float4v*)(base);
    float4v a1 = *(const float4v*)(base + 4);
    float4v a2 = *(const float4v*)(base + 8);
    float4v a3 = *(const float4v*)(base + 12);
    r[0]=a0.x; r[1]=a0.y; r[2]=a0.z; r[3]=a0.w;
    r[4]=a1.x; r[5]=a1.y; r[6]=a1.z; r[7]=a1.w;
    r[8]=a2.x; r[9]=a2.y; r[10]=a2.z; r[11]=a2.w;
    r[12]=a3.x; r[13]=a3.y; r[14]=a3.z; r[15]=a3.w;
}

// ---------------- convert emb f32 -> bf16; block 0 also zeroes accumulators ----------------
__global__ __launch_bounds__(256) void conv_init(
    const float* __restrict__ src, unsigned short* __restrict__ dst, float* __restrict__ acc)
{
    if (blockIdx.x == 0 && threadIdx.x < ACC_F) acc[threadIdx.x] = 0.f;
    const size_t i = ((size_t)blockIdx.x * 256 + threadIdx.x) * 8;
    float4v a = *(const float4v*)(src + i);
    float4v b = *(const float4v*)(src + i + 4);
    uint4 w = {pk2(a.x,a.y), pk2(a.z,a.w), pk2(b.x,b.y), pk2(b.z,b.w)};
    *(uint4*)(dst + i) = w;
}

// XCD-locality decode: 528 blocks = 66 x 8. Heuristic XCD = id%8; ids with equal id%8
// walk a clustered order over (row-group, col-group) pairs (groups of 4 tiles) so each
// XCD's instantaneous working set is ~3 MB (< 4 MB per-XCD L2).
__device__ __forceinline__ void decode_pair(int id, int& bi, int& bj) {
    int L = (id & 7) * 66 + (id >> 3);   // position in the clustered enumeration
    int gi = 0, gj = 0;
    for (;;) {
        const int cnt = (gi == gj) ? 10 : 16;
        if (L < cnt) break;
        L -= cnt;
        gj++; if (gj == 8) { gi++; gj = gi; }
    }
    if (gi == gj) {        // 10 pairs u<=v in a 4x4 group
        int u = 0, c = 4;
        while (L >= c) { L -= c; u++; c--; }
        bi = gi * 4 + u; bj = gj * 4 + u + L;
    } else {
        bi = gi * 4 + (L >> 2); bj = gj * 4 + (L & 3);
    }
}

// ---------------- Kernel B: symmetric Gram GEMM + masked bidirectional KL + finalize ----------------
template<bool PRE>
__global__ __launch_bounds__(256) void gram_kl(
    const float* __restrict__ embf, const unsigned short* __restrict__ embb,
    const float* __restrict__ rp, float* __restrict__ acc,
    unsigned int* __restrict__ out)
{
    __shared__ char smem[40960];
    __shared__ float red[8];
    __shared__ int islast;
    __shared__ float fin[96];
    // K-loop view (16 KB):
    __hip_bfloat16* tA = (__hip_bfloat16*)smem;            // [128][32] bf16, chunk-swizzled
    __hip_bfloat16* tB = (__hip_bfloat16*)(smem + 8192);
    // epilogue view (40 KB, reused): rows stride 20 f32, [16] = ne
    float* lpI = (float*)smem;
    float* qI  = (float*)(smem + 10240);
    float* lpJ = (float*)(smem + 20480);
    float* qJ  = (float*)(smem + 30720);

    int bi, bj;
    decode_pair((int)blockIdx.x, bi, bj);

    const int t = threadIdx.x;
    const int lane = t & 63, wid = t >> 6;
    const int wi0 = (wid >> 1) * 64, wj0 = (wid & 1) * 64;
    const int lrow = lane & 15, quad = lane >> 4;

    // staging: thread t covers rows {t>>2, 64+(t>>2)}, 16B chunk cp (XOR-swizzled placement)
    const int row0 = t >> 2, cp = t & 3;
    const int row1 = 64 + row0;
    const int sw0 = cp ^ ((row0 >> 1) & 3);
    const int oA0 = row0 * 32 + sw0 * 8, oA1 = row1 * 32 + sw0 * 8;

    float4v accf[4][4];
#pragma unroll
    for (int a = 0; a < 4; a++)
#pragma unroll
        for (int b = 0; b < 4; b++) { accf[a][b].x=0.f; accf[a][b].y=0.f; accf[a][b].z=0.f; accf[a][b].w=0.f; }

    // fragment read offsets (swizzle depends only on row)
    int roA[4], roB[4];
#pragma unroll
    for (int f = 0; f < 4; f++) {
        const int ra = wi0 + f * 16 + lrow;
        const int rb = wj0 + f * 16 + lrow;
        roA[f] = ra * 32 + (quad ^ ((ra >> 1) & 3)) * 8;
        roB[f] = rb * 32 + (quad ^ ((rb >> 1) & 3)) * 8;
    }

    if (PRE) {
        const unsigned short* gA = embb + (size_t)(bi * 128) * HDIM;
        const unsigned short* gB = embb + (size_t)(bj * 128) * HDIM;
        uint4 va0 = *(const uint4*)(gA + (size_t)row0 * HDIM + cp * 8);
        uint4 va1 = *(const uint4*)(gA + (size_t)row1 * HDIM + cp * 8);
        uint4 vb0 = *(const uint4*)(gB + (size_t)row0 * HDIM + cp * 8);
        uint4 vb1 = *(const uint4*)(gB + (size_t)row1 * HDIM + cp * 8);
        for (int kt = 0; kt < HDIM; kt += 32) {
            __syncthreads();                 // prev iter's fragment reads done
            *(uint4*)(tA + oA0) = va0;
            *(uint4*)(tA + oA1) = va1;
            *(uint4*)(tB + oA0) = vb0;
            *(uint4*)(tB + oA1) = vb1;
            __syncthreads();
            const int kn = (kt + 32 < HDIM) ? (kt + 32) : kt;   // uniform; last reload harmless
            va0 = *(const uint4*)(gA + (size_t)row0 * HDIM + kn + cp * 8);
            va1 = *(const uint4*)(gA + (size_t)row1 * HDIM + kn + cp * 8);
            vb0 = *(const uint4*)(gB + (size_t)row0 * HDIM + kn + cp * 8);
            vb1 = *(const uint4*)(gB + (size_t)row1 * HDIM + kn + cp * 8);
            short8 a[4], b[4];
#pragma unroll
            for (int f = 0; f < 4; f++) {
                a[f] = *(const short8*)(tA + roA[f]);
                b[f] = *(const short8*)(tB + roB[f]);
            }
#pragma unroll
            for (int fi = 0; fi < 4; fi++)
#pragma unroll
                for (int fj = 0; fj < 4; fj++)
                    accf[fi][fj] = __builtin_amdgcn_mfma_f32_16x16x32_bf16(
                        a[fi], b[fj], accf[fi][fj], 0, 0, 0);
        }
    } else {
        // fallback (ws too small): in-loop f32->bf16 conversion, same pipeline
        const float* gA = embf + (size_t)(bi * 128) * HDIM;
        const float* gB = embf + (size_t)(bj * 128) * HDIM;
        float4v a00,a01,a10,a11,b00,b01,b10,b11;
        {
            const float* pa0 = gA + (size_t)row0 * HDIM + cp * 8;
            const float* pa1 = gA + (size_t)row1 * HDIM + cp * 8;
            const float* pb0 = gB + (size_t)row0 * HDIM + cp * 8;
            const float* pb1 = gB + (size_t)row1 * HDIM + cp * 8;
            a00=*(const float4v*)pa0; a01=*(const float4v*)(pa0+4);
            a10=*(const float4v*)pa1; a11=*(const float4v*)(pa1+4);
            b00=*(const float4v*)pb0; b01=*(const float4v*)(pb0+4);
            b10=*(const float4v*)pb1; b11=*(const float4v*)(pb1+4);
        }
        for (int kt = 0; kt < HDIM; kt += 32) {
            uint4 wa0 = {pk2(a00.x,a00.y), pk2(a00.z,a00.w), pk2(a01.x,a01.y), pk2(a01.z,a01.w)};
            uint4 wa1 = {pk2(a10.x,a10.y), pk2(a10.z,a10.w), pk2(a11.x,a11.y), pk2(a11.z,a11.w)};
            uint4 wb0 = {pk2(b00.x,b00.y), pk2(b00.z,b00.w), pk2(b01.x,b01.y), pk2(b01.z,b01.w)};
            uint4 wb1 = {pk2(b10.x,b10.y), pk2(b10.z,b10.w), pk2(b11.x,b11.y), pk2(b11.z,b11.w)};
            __syncthreads();
            *(uint4*)(tA + oA0) = wa0;
            *(uint4*)(tA + oA1) = wa1;
            *(uint4*)(tB + oA0) = wb0;
            *(uint4*)(tB + oA1) = wb1;
            __syncthreads();
            const int kn = (kt + 32 < HDIM) ? (kt + 32) : kt;
            const float* pa0 = gA + (size_t)row0 * HDIM + kn + cp * 8;
            const float* pa1 = gA + (size_t)row1 * HDIM + kn + cp * 8;
            const float* pb0 = gB + (size_t)row0 * HDIM + kn + cp * 8;
            const float* pb1 = gB + (size_t)row1 * HDIM + kn + cp * 8;
            a00=*(const float4v*)pa0; a01=*(const float4v*)(pa0+4);
            a10=*(const float4v*)pa1; a11=*(const float4v*)(pa1+4);
            b00=*(const float4v*)pb0; b01=*(const float4v*)(pb0+4);
            b10=*(const float4v*)pb1; b11=*(const float4v*)(pb1+4);
            short8 a[4], b[4];
#pragma unroll
            for (int f = 0; f < 4; f++) {
                a[f] = *(const short8*)(tA + roA[f]);
                b[f] = *(const short8*)(tB + roB[f]);
            }
#pragma unroll
            for (int fi = 0; fi < 4; fi++)
#pragma unroll
                for (int fj = 0; fj < 4; fj++)
                    accf[fi][fj] = __builtin_amdgcn_mfma_f32_16x16x32_bf16(
                        a[fi], b[fj], accf[fi][fj], 0, 0, 0);
        }
    }
    __syncthreads();  // K-loop LDS reads done before epilogue overwrites smem

    // ---- epilogue staging: waves 0,1 -> I rows; waves 2,3 -> J rows ----
    {
        float p[16], lp[16], q[16], ne;
        const bool iSide = (t < 128);
        const int rloc = iSide ? t : (t - 128);
        const int grow = (iSide ? bi : bj) * 128 + rloc;
        row16f(rp + (size_t)grow * NE, p);
        lsm16(p, lp, q, ne);
        float* dl = (iSide ? lpI : lpJ) + rloc * 20;
        float* dq = (iSide ? qI  : qJ ) + rloc * 20;
        float4v l0 = {lp[0],lp[1],lp[2],lp[3]},   l1 = {lp[4],lp[5],lp[6],lp[7]};
        float4v l2 = {lp[8],lp[9],lp[10],lp[11]}, l3 = {lp[12],lp[13],lp[14],lp[15]};
        *(float4v*)dl = l0; *(float4v*)(dl+4) = l1; *(float4v*)(dl+8) = l2; *(float4v*)(dl+12) = l3;
        float4v q0 = {q[0],q[1],q[2],q[3]},   q1 = {q[4],q[5],q[6],q[7]};
        float4v q2 = {q[8],q[9],q[10],q[11]}, q3 = {q[12],q[13],q[14],q[15]};
        *(float4v*)dq = q0; *(float4v*)(dq+4) = q1; *(float4v*)(dq+8) = q2; *(float4v*)(dq+12) = q3;
        dq[16] = ne;

        if (bi == bj && iSide) {   // fold row stats (each row in exactly one diag block's I side)
            float ent = 0.f, eff = 0.f;
#pragma unroll
            for (int e = 0; e < 16; e++) {
                ent += p[e] * logf(p[e] + 1e-8f);
                if (p[e] < 0.1f) eff += p[e];
            }
#pragma unroll
            for (int e = 0; e < 18; e++) {
                float v = (e < 16) ? p[e] : ((e == 16) ? ent : eff);
#pragma unroll
                for (int off = 32; off > 0; off >>= 1) v += __shfl_down(v, off);
                if (lane == 0) atomicAdd(&acc[e], v);
            }
        }
    }
    __syncthreads();

    float klacc = 0.f, cntacc = 0.f;

    // ---- forward: kl[i,j] = ne_j - lp_i.q_j  (C layout: col=lane&15, row=quad*4+reg)
    {
        float qreg[4][16], nereg[4];
        int jg[4];
#pragma unroll
        for (int fj = 0; fj < 4; fj++) {
            const int jc = wj0 + fj * 16 + lrow;
            ldsrow16(qJ + jc * 20, qreg[fj]);
            nereg[fj] = qJ[jc * 20 + 16];
            jg[fj] = bj * 128 + jc;
        }
#pragma unroll
        for (int fi = 0; fi < 4; fi++) {
#pragma unroll
            for (int rg = 0; rg < 4; rg++) {
                const int rr = wi0 + fi * 16 + quad * 4 + rg;
                float lpr[16];
                ldsrow16(lpI + rr * 20, lpr);
                const int ig = bi * 128 + rr;
#pragma unroll
                for (int fj = 0; fj < 4; fj++) {
                    float d = 0.f;
#pragma unroll
                    for (int e = 0; e < 16; e++) d += lpr[e] * qreg[fj][e];
                    const float g = accf[fi][fj][rg];
                    if ((g > 0.f) && (ig != jg[fj])) { klacc += nereg[fj] - d; cntacc += 1.f; }
                }
            }
        }
    }

    // ---- reverse (off-diagonal only): kl[j,i] = ne_i - lp_j.q_i
    if (bi != bj) {
        float lpjr[4][16];
#pragma unroll
        for (int fj = 0; fj < 4; fj++) {
            const int jc = wj0 + fj * 16 + lrow;
            ldsrow16(lpJ + jc * 20, lpjr[fj]);
        }
#pragma unroll
        for (int fi = 0; fi < 4; fi++) {
#pragma unroll
            for (int rg = 0; rg < 4; rg++) {
                const int rr = wi0 + fi * 16 + quad * 4 + rg;
                float qrow[16];
                ldsrow16(qI + rr * 20, qrow);
                const float nei = qI[rr * 20 + 16];
#pragma unroll
                for (int fj = 0; fj < 4; fj++) {
                    float d = 0.f;
#pragma unroll
                    for (int e = 0; e < 16; e++) d += lpjr[fj][e] * qrow[e];
                    const float g = accf[fi][fj][rg];
                    if (g > 0.f) { klacc += nei - d; cntacc += 1.f; }
                }
            }
        }
    }

    // block reduce -> striped atomics
#pragma unroll
    for (int off = 32; off > 0; off >>= 1) {
        klacc  += __shfl_down(klacc, off);
        cntacc += __shfl_down(cntacc, off);
    }
    if (lane == 0) { red[wid] = klacc; red[4 + wid] = cntacc; }
    __syncthreads();
    if (t == 0) {
        atomicAdd(&acc[18 + ((int)blockIdx.x & 31)], red[0] + red[1] + red[2] + red[3]);
        atomicAdd(&acc[50 + ((int)blockIdx.x & 31)], red[4] + red[5] + red[6] + red[7]);
        // release-scoped ticket: buffer_wbl2 only -- does NOT invalidate clean L2 lines
        // (__threadfence() emits buffer_inv, which nuked embb from L2 every block: R5 regression)
        const unsigned got = __hip_atomic_fetch_add((unsigned int*)(acc + 82), 1u,
                                                    __ATOMIC_RELEASE, __HIP_MEMORY_SCOPE_AGENT);
        islast = (got == NBLK - 1) ? 1 : 0;
    }
    __syncthreads();

    // ---- last-finished block finalizes ----
    if (islast) {
        if (t == 0)   // acquire pairs with all writers' releases
            (void)__hip_atomic_load((unsigned int*)(acc + 82), __ATOMIC_ACQUIRE,
                                    __HIP_MEMORY_SCOPE_AGENT);
        __syncthreads();
        if (t < 82)   // agent-scope loads read the coherent point
            fin[t] = __hip_atomic_load(&acc[t], __ATOMIC_RELAXED, __HIP_MEMORY_SCOPE_AGENT);
        __syncthreads();
        if (t == 0) {
            float u[16], usum = 0.f;
#pragma unroll
            for (int e = 0; e < 16; e++) { u[e] = fin[e] / (float)BROWS; usum += u[e]; }
            const float mean = usum / 16.f;
            float var = 0.f;
#pragma unroll
            for (int e = 0; e < 16; e++) { float dd = u[e] - mean; var += dd * dd; }
            var /= 15.f;
            const float lb  = var * 256.f;
            const float ent = fin[16] / (float)BROWS;
            const float eff = fin[17] / (float)BROWS;
            float kl = 0.f, cnt = 0.f;
#pragma unroll
            for (int s = 0; s < 32; s++) { kl += fin[18 + s]; cnt += fin[50 + s]; }
            const float cons = (cnt > 0.f) ? (kl / fmaxf(cnt, 1.f)) : 0.f;
            const float total = lb + ent + eff + cons;
            // low16 = exact bf16(total); full word ~ f32(total) (rel err < 2^-9)
            const unsigned fb   = __float_as_uint(total);
            const unsigned hi   = fb >> 16;
            const unsigned mant = fb & 0xFFFFu;
            const unsigned rnd  = (mant > 0x8000u || (mant == 0x8000u && (hi & 1))) ? 1u : 0u;
            out[0] = (fb & 0xFFFF0000u) | ((hi + rnd) & 0xFFFFu);
        }
    }
}

extern "C" void kernel_launch(void* const* d_in, const int* in_sizes, int n_in,
                              void* d_out, int out_size, void* d_ws, size_t ws_size,
                              hipStream_t stream) {
    const float* rp  = (const float*)d_in[0];   // [4096,16]   f32
    const float* emb = (const float*)d_in[1];   // [4096,1024] f32
    float* acc = (float*)d_ws;
    unsigned short* embb = (unsigned short*)((char*)d_ws + ACC_F * sizeof(float));
    (void)in_sizes; (void)n_in; (void)out_size;

    const size_t need = ACC_F * sizeof(float) + (size_t)BROWS * HDIM * 2;
    const bool pre = (ws_size >= need);   // constant across calls -> capture-safe

    if (pre) {
        conv_init<<<(BROWS * HDIM) / (256 * 8), 256, 0, stream>>>(emb, embb, acc);
        gram_kl<true><<<NBLK, 256, 0, stream>>>(emb, embb, rp, acc, (unsigned int*)d_out);
    } else {
        conv_init<<<1, 256, 0, stream>>>(emb, embb, acc);  // still zeroes acc (block 0)
        gram_kl<false><<<NBLK, 256, 0, stream>>>(emb, (const unsigned short*)nullptr, rp, acc,
                                                 (unsigned int*)d_out);
    }
}

// Round 7
// 125.702 us; speedup vs baseline: 1.3212x; 1.0887x over previous
//
#include <hip/hip_runtime.h>
#include <hip/hip_bf16.h>

// Problem constants (fixed by reference setup_inputs)
#define BROWS 4096
#define NE    16
#define HDIM  1024
// ws floats: [0..15] usage, [16] ent, [17] eff, [18..49] kl, [50..81] cnt, [82] ticket
#define ACC_F 128
#define NTILE 32                              // 4096 / 128
#define NBLK  (NTILE * (NTILE + 1) / 2)       // 528 upper-triangular block pairs

typedef __attribute__((ext_vector_type(8))) short short8;   // 8 bf16 (4 VGPRs)
typedef __attribute__((ext_vector_type(4))) float float4v;  // 4 f32

// f32 -> bf16 round-to-nearest-even, low 16 bits
__device__ __forceinline__ unsigned bf16rne(float f) {
    const unsigned u = __float_as_uint(f);
    return (u + 0x7FFFu + ((u >> 16) & 1u)) >> 16;
}
__device__ __forceinline__ unsigned pk2(float lo, float hi) {
    return bf16rne(lo) | (bf16rne(hi) << 16);
}

__device__ __forceinline__ void row16f(const float* src, float* p) {
    const float4v* pv = (const float4v*)src;
    float4v a0 = pv[0], a1 = pv[1], a2 = pv[2], a3 = pv[3];
    p[0]=a0.x; p[1]=a0.y; p[2]=a0.z; p[3]=a0.w;
    p[4]=a1.x; p[5]=a1.y; p[6]=a1.z; p[7]=a1.w;
    p[8]=a2.x; p[9]=a2.y; p[10]=a2.z; p[11]=a2.w;
    p[12]=a3.x; p[13]=a3.y; p[14]=a3.z; p[15]=a3.w;
}

// log_softmax of a 16-vector
__device__ __forceinline__ void lsm16(const float* p, float* lp, float* q, float& ne) {
    float m = p[0];
#pragma unroll
    for (int e = 1; e < 16; e++) m = fmaxf(m, p[e]);
    float s = 0.f;
#pragma unroll
    for (int e = 0; e < 16; e++) s += expf(p[e] - m);
    const float ls = logf(s);
    ne = 0.f;
#pragma unroll
    for (int e = 0; e < 16; e++) {
        lp[e] = p[e] - m - ls;
        q[e]  = expf(lp[e]);
        ne   += q[e] * lp[e];
    }
}

// read a stride-20 LDS row (16 floats)
__device__ __forceinline__ void ldsrow16(const float* base, float* r) {
    float4v a0 = *(const float4v*)(base);
    float4v a1 = *(const float4v*)(base + 4);
    float4v a2 = *(const float4v*)(base + 8);
    float4v a3 = *(const float4v*)(base + 12);
    r[0]=a0.x; r[1]=a0.y; r[2]=a0.z; r[3]=a0.w;
    r[4]=a1.x; r[5]=a1.y; r[6]=a1.z; r[7]=a1.w;
    r[8]=a2.x; r[9]=a2.y; r[10]=a2.z; r[11]=a2.w;
    r[12]=a3.x; r[13]=a3.y; r[14]=a3.z; r[15]=a3.w;
}

// ---------------- convert emb f32 -> bf16; block 0 also zeroes accumulators ----------------
__global__ __launch_bounds__(256) void conv_init(
    const float* __restrict__ src, unsigned short* __restrict__ dst, float* __restrict__ acc)
{
    if (blockIdx.x == 0 && threadIdx.x < ACC_F) acc[threadIdx.x] = 0.f;
    const size_t i = ((size_t)blockIdx.x * 256 + threadIdx.x) * 8;
    float4v a = *(const float4v*)(src + i);
    float4v b = *(const float4v*)(src + i + 4);
    uint4 w = {pk2(a.x,a.y), pk2(a.z,a.w), pk2(b.x,b.y), pk2(b.z,b.w)};
    *(uint4*)(dst + i) = w;
}

// XCD-locality decode: 528 = 66 x 8; ids with equal id%8 walk a clustered order over
// 4-tile row/col groups so each XCD's instantaneous working set is ~3 MB (< 4 MB L2).
__device__ __forceinline__ void decode_pair(int id, int& bi, int& bj) {
    int L = (id & 7) * 66 + (id >> 3);
    int gi = 0, gj = 0;
    for (;;) {
        const int cnt = (gi == gj) ? 10 : 16;
        if (L < cnt) break;
        L -= cnt;
        gj++; if (gj == 8) { gi++; gj = gi; }
    }
    if (gi == gj) {
        int u = 0, c = 4;
        while (L >= c) { L -= c; u++; c--; }
        bi = gi * 4 + u; bj = gj * 4 + u + L;
    } else {
        bi = gi * 4 + (L >> 2); bj = gj * 4 + (L & 3);
    }
}

// ---------------- Kernel B: symmetric Gram GEMM + masked bidirectional KL + finalize ----------------
// 512 threads / 8 waves per block: wave owns a 32x64 quadrant (2x4 16x16 frags).
// 2 blocks/CU x 8 waves = 4 waves/SIMD -- 2x the latency hiding of the 256-thread version.
template<bool PRE>
__global__ __launch_bounds__(512, 4) void gram_kl(
    const float* __restrict__ embf, const unsigned short* __restrict__ embb,
    const float* __restrict__ rp, float* __restrict__ acc,
    unsigned int* __restrict__ out)
{
    __shared__ char smem[40960];
    __shared__ float red[16];
    __shared__ int islast;
    __shared__ float fin[96];
    // K-loop view (16 KB):
    __hip_bfloat16* tA = (__hip_bfloat16*)smem;            // [128][32] bf16, chunk-swizzled
    __hip_bfloat16* tB = (__hip_bfloat16*)(smem + 8192);
    // epilogue view (40 KB, reused): rows stride 20 f32, [16] = ne
    float* lpI = (float*)smem;
    float* qI  = (float*)(smem + 10240);
    float* lpJ = (float*)(smem + 20480);
    float* qJ  = (float*)(smem + 30720);

    int bi, bj;
    decode_pair((int)blockIdx.x, bi, bj);

    const int t = threadIdx.x;
    const int lane = t & 63, wid = t >> 6;           // 8 waves
    const int wi0 = (wid >> 1) * 32, wj0 = (wid & 1) * 64;   // 32x64 quadrant
    const int lrow = lane & 15, quad = lane >> 4;

    // staging: 512 threads cover 128 rows x 4 chunks in one round; 1 chunk per tile each
    const int row = t >> 2, cp = t & 3;
    const int sw  = cp ^ ((row >> 1) & 3);           // XOR bank swizzle
    const int off = row * 32 + sw * 8;

    float4v accf[2][4];
#pragma unroll
    for (int a = 0; a < 2; a++)
#pragma unroll
        for (int b = 0; b < 4; b++) { accf[a][b].x=0.f; accf[a][b].y=0.f; accf[a][b].z=0.f; accf[a][b].w=0.f; }

    // fragment read offsets (swizzle depends only on row)
    int roA[2], roB[4];
#pragma unroll
    for (int f = 0; f < 2; f++) {
        const int ra = wi0 + f * 16 + lrow;
        roA[f] = ra * 32 + (quad ^ ((ra >> 1) & 3)) * 8;
    }
#pragma unroll
    for (int f = 0; f < 4; f++) {
        const int rb = wj0 + f * 16 + lrow;
        roB[f] = rb * 32 + (quad ^ ((rb >> 1) & 3)) * 8;
    }

    if (PRE) {
        const unsigned short* gA = embb + (size_t)(bi * 128) * HDIM;
        const unsigned short* gB = embb + (size_t)(bj * 128) * HDIM;
        uint4 va = *(const uint4*)(gA + (size_t)row * HDIM + cp * 8);
        uint4 vb = *(const uint4*)(gB + (size_t)row * HDIM + cp * 8);
        for (int kt = 0; kt < HDIM; kt += 32) {
            __syncthreads();                 // prev iter's fragment reads done
            *(uint4*)(tA + off) = va;
            *(uint4*)(tB + off) = vb;
            __syncthreads();
            const int kn = (kt + 32 < HDIM) ? (kt + 32) : kt;   // uniform; last reload harmless
            va = *(const uint4*)(gA + (size_t)row * HDIM + kn + cp * 8);
            vb = *(const uint4*)(gB + (size_t)row * HDIM + kn + cp * 8);
            short8 a[2], b[4];
#pragma unroll
            for (int f = 0; f < 2; f++) a[f] = *(const short8*)(tA + roA[f]);
#pragma unroll
            for (int f = 0; f < 4; f++) b[f] = *(const short8*)(tB + roB[f]);
#pragma unroll
            for (int fi = 0; fi < 2; fi++)
#pragma unroll
                for (int fj = 0; fj < 4; fj++)
                    accf[fi][fj] = __builtin_amdgcn_mfma_f32_16x16x32_bf16(
                        a[fi], b[fj], accf[fi][fj], 0, 0, 0);
        }
    } else {
        // fallback (ws too small): in-loop f32->bf16 conversion, same pipeline
        const float* gA = embf + (size_t)(bi * 128) * HDIM;
        const float* gB = embf + (size_t)(bj * 128) * HDIM;
        float4v a0, a1, b0, b1;
        {
            const float* pa = gA + (size_t)row * HDIM + cp * 8;
            const float* pb = gB + (size_t)row * HDIM + cp * 8;
            a0 = *(const float4v*)pa; a1 = *(const float4v*)(pa + 4);
            b0 = *(const float4v*)pb; b1 = *(const float4v*)(pb + 4);
        }
        for (int kt = 0; kt < HDIM; kt += 32) {
            uint4 wa = {pk2(a0.x,a0.y), pk2(a0.z,a0.w), pk2(a1.x,a1.y), pk2(a1.z,a1.w)};
            uint4 wb = {pk2(b0.x,b0.y), pk2(b0.z,b0.w), pk2(b1.x,b1.y), pk2(b1.z,b1.w)};
            __syncthreads();
            *(uint4*)(tA + off) = wa;
            *(uint4*)(tB + off) = wb;
            __syncthreads();
            const int kn = (kt + 32 < HDIM) ? (kt + 32) : kt;
            const float* pa = gA + (size_t)row * HDIM + kn + cp * 8;
            const float* pb = gB + (size_t)row * HDIM + kn + cp * 8;
            a0 = *(const float4v*)pa; a1 = *(const float4v*)(pa + 4);
            b0 = *(const float4v*)pb; b1 = *(const float4v*)(pb + 4);
            short8 a[2], b[4];
#pragma unroll
            for (int f = 0; f < 2; f++) a[f] = *(const short8*)(tA + roA[f]);
#pragma unroll
            for (int f = 0; f < 4; f++) b[f] = *(const short8*)(tB + roB[f]);
#pragma unroll
            for (int fi = 0; fi < 2; fi++)
#pragma unroll
                for (int fj = 0; fj < 4; fj++)
                    accf[fi][fj] = __builtin_amdgcn_mfma_f32_16x16x32_bf16(
                        a[fi], b[fj], accf[fi][fj], 0, 0, 0);
        }
    }
    __syncthreads();  // K-loop LDS reads done before epilogue overwrites smem

    // ---- epilogue staging: t<128 -> I rows; t in [128,256) -> J rows; rest idle ----
    {
        float p[16], lp[16], q[16], ne;
        const bool iSide = (t < 128);
        if (t < 256) {
            const int rloc = iSide ? t : (t - 128);
            const int grow = (iSide ? bi : bj) * 128 + rloc;
            row16f(rp + (size_t)grow * NE, p);
            lsm16(p, lp, q, ne);
            float* dl = (iSide ? lpI : lpJ) + rloc * 20;
            float* dq = (iSide ? qI  : qJ ) + rloc * 20;
            float4v l0 = {lp[0],lp[1],lp[2],lp[3]},   l1 = {lp[4],lp[5],lp[6],lp[7]};
            float4v l2 = {lp[8],lp[9],lp[10],lp[11]}, l3 = {lp[12],lp[13],lp[14],lp[15]};
            *(float4v*)dl = l0; *(float4v*)(dl+4) = l1; *(float4v*)(dl+8) = l2; *(float4v*)(dl+12) = l3;
            float4v q0 = {q[0],q[1],q[2],q[3]},   q1 = {q[4],q[5],q[6],q[7]};
            float4v q2 = {q[8],q[9],q[10],q[11]}, q3 = {q[12],q[13],q[14],q[15]};
            *(float4v*)dq = q0; *(float4v*)(dq+4) = q1; *(float4v*)(dq+8) = q2; *(float4v*)(dq+12) = q3;
            dq[16] = ne;
        }
        if (bi == bj && iSide) {   // fold row stats (each row in exactly one diag block's I side)
            float ent = 0.f, eff = 0.f;
#pragma unroll
            for (int e = 0; e < 16; e++) {
                ent += p[e] * logf(p[e] + 1e-8f);
                if (p[e] < 0.1f) eff += p[e];
            }
#pragma unroll
            for (int e = 0; e < 18; e++) {
                float v = (e < 16) ? p[e] : ((e == 16) ? ent : eff);
#pragma unroll
                for (int off2 = 32; off2 > 0; off2 >>= 1) v += __shfl_down(v, off2);
                if (lane == 0) atomicAdd(&acc[e], v);
            }
        }
    }
    __syncthreads();

    float klacc = 0.f, cntacc = 0.f;

    // ---- forward: kl[i,j] = ne_j - lp_i.q_j  (C layout: col=lane&15, row=quad*4+reg)
    {
        float qreg[4][16], nereg[4];
        int jg[4];
#pragma unroll
        for (int fj = 0; fj < 4; fj++) {
            const int jc = wj0 + fj * 16 + lrow;
            ldsrow16(qJ + jc * 20, qreg[fj]);
            nereg[fj] = qJ[jc * 20 + 16];
            jg[fj] = bj * 128 + jc;
        }
#pragma unroll
        for (int fi = 0; fi < 2; fi++) {
#pragma unroll
            for (int rg = 0; rg < 4; rg++) {
                const int rr = wi0 + fi * 16 + quad * 4 + rg;
                float lpr[16];
                ldsrow16(lpI + rr * 20, lpr);
                const int ig = bi * 128 + rr;
#pragma unroll
                for (int fj = 0; fj < 4; fj++) {
                    float d = 0.f;
#pragma unroll
                    for (int e = 0; e < 16; e++) d += lpr[e] * qreg[fj][e];
                    const float g = accf[fi][fj][rg];
                    if ((g > 0.f) && (ig != jg[fj])) { klacc += nereg[fj] - d; cntacc += 1.f; }
                }
            }
        }
    }

    // ---- reverse (off-diagonal only): kl[j,i] = ne_i - lp_j.q_i
    if (bi != bj) {
        float lpjr[4][16];
#pragma unroll
        for (int fj = 0; fj < 4; fj++) {
            const int jc = wj0 + fj * 16 + lrow;
            ldsrow16(lpJ + jc * 20, lpjr[fj]);
        }
#pragma unroll
        for (int fi = 0; fi < 2; fi++) {
#pragma unroll
            for (int rg = 0; rg < 4; rg++) {
                const int rr = wi0 + fi * 16 + quad * 4 + rg;
                float qrow[16];
                ldsrow16(qI + rr * 20, qrow);
                const float nei = qI[rr * 20 + 16];
#pragma unroll
                for (int fj = 0; fj < 4; fj++) {
                    float d = 0.f;
#pragma unroll
                    for (int e = 0; e < 16; e++) d += lpjr[fj][e] * qrow[e];
                    const float g = accf[fi][fj][rg];
                    if (g > 0.f) { klacc += nei - d; cntacc += 1.f; }
                }
            }
        }
    }

    // block reduce -> striped atomics
#pragma unroll
    for (int off2 = 32; off2 > 0; off2 >>= 1) {
        klacc  += __shfl_down(klacc, off2);
        cntacc += __shfl_down(cntacc, off2);
    }
    if (lane == 0) { red[wid] = klacc; red[8 + wid] = cntacc; }
    __syncthreads();
    if (t == 0) {
        float k = 0.f, c = 0.f;
#pragma unroll
        for (int w = 0; w < 8; w++) { k += red[w]; c += red[8 + w]; }
        atomicAdd(&acc[18 + ((int)blockIdx.x & 31)], k);
        atomicAdd(&acc[50 + ((int)blockIdx.x & 31)], c);
        // release-scoped ticket: wbL2 only -- must NOT invalidate L2 (R5 regression was
        // __threadfence()'s buffer_inv nuking embb from L2 on every block completion)
        const unsigned got = __hip_atomic_fetch_add((unsigned int*)(acc + 82), 1u,
                                                    __ATOMIC_RELEASE, __HIP_MEMORY_SCOPE_AGENT);
        islast = (got == NBLK - 1) ? 1 : 0;
    }
    __syncthreads();

    // ---- last-finished block finalizes ----
    if (islast) {
        if (t == 0)   // acquire pairs with all writers' releases
            (void)__hip_atomic_load((unsigned int*)(acc + 82), __ATOMIC_ACQUIRE,
                                    __HIP_MEMORY_SCOPE_AGENT);
        __syncthreads();
        if (t < 82)   // agent-scope loads read the coherent point
            fin[t] = __hip_atomic_load(&acc[t], __ATOMIC_RELAXED, __HIP_MEMORY_SCOPE_AGENT);
        __syncthreads();
        if (t == 0) {
            float u[16], usum = 0.f;
#pragma unroll
            for (int e = 0; e < 16; e++) { u[e] = fin[e] / (float)BROWS; usum += u[e]; }
            const float mean = usum / 16.f;
            float var = 0.f;
#pragma unroll
            for (int e = 0; e < 16; e++) { float dd = u[e] - mean; var += dd * dd; }
            var /= 15.f;
            const float lb  = var * 256.f;
            const float ent = fin[16] / (float)BROWS;
            const float eff = fin[17] / (float)BROWS;
            float kl = 0.f, cnt = 0.f;
#pragma unroll
            for (int s = 0; s < 32; s++) { kl += fin[18 + s]; cnt += fin[50 + s]; }
            const float cons = (cnt > 0.f) ? (kl / fmaxf(cnt, 1.f)) : 0.f;
            const float total = lb + ent + eff + cons;
            // low16 = exact bf16(total); full word ~ f32(total) (rel err < 2^-9)
            const unsigned fb   = __float_as_uint(total);
            const unsigned hi   = fb >> 16;
            const unsigned mant = fb & 0xFFFFu;
            const unsigned rnd  = (mant > 0x8000u || (mant == 0x8000u && (hi & 1))) ? 1u : 0u;
            out[0] = (fb & 0xFFFF0000u) | ((hi + rnd) & 0xFFFFu);
        }
    }
}

extern "C" void kernel_launch(void* const* d_in, const int* in_sizes, int n_in,
                              void* d_out, int out_size, void* d_ws, size_t ws_size,
                              hipStream_t stream) {
    const float* rp  = (const float*)d_in[0];   // [4096,16]   f32
    const float* emb = (const float*)d_in[1];   // [4096,1024] f32
    float* acc = (float*)d_ws;
    unsigned short* embb = (unsigned short*)((char*)d_ws + ACC_F * sizeof(float));
    (void)in_sizes; (void)n_in; (void)out_size;

    const size_t need = ACC_F * sizeof(float) + (size_t)BROWS * HDIM * 2;
    const bool pre = (ws_size >= need);   // constant across calls -> capture-safe

    if (pre) {
        conv_init<<<(BROWS * HDIM) / (256 * 8), 256, 0, stream>>>(emb, embb, acc);
        gram_kl<true><<<NBLK, 512, 0, stream>>>(emb, embb, rp, acc, (unsigned int*)d_out);
    } else {
        conv_init<<<1, 256, 0, stream>>>(emb, embb, acc);  // still zeroes acc (block 0)
        gram_kl<false><<<NBLK, 512, 0, stream>>>(emb, (const unsigned short*)nullptr, rp, acc,
                                                 (unsigned int*)d_out);
    }
}

// Round 8
// 117.930 us; speedup vs baseline: 1.4083x; 1.0659x over previous
//
#include <hip/hip_runtime.h>
#include <hip/hip_bf16.h>

// Problem constants (fixed by reference setup_inputs)
#define BROWS 4096
#define NE    16
#define HDIM  1024
// ws floats: [0..15] usage, [16] ent, [17] eff, [18..49] kl, [50..81] cnt, [82] ticket
#define ACC_F 128
#define NTILE 32                              // 4096 / 128
#define NBLK  (NTILE * (NTILE + 1) / 2)       // 528 upper-triangular block pairs

typedef __attribute__((ext_vector_type(8))) short short8;   // 8 bf16 (4 VGPRs)
typedef __attribute__((ext_vector_type(4))) float float4v;  // 4 f32

// f32 -> bf16 round-to-nearest-even, low 16 bits
__device__ __forceinline__ unsigned bf16rne(float f) {
    const unsigned u = __float_as_uint(f);
    return (u + 0x7FFFu + ((u >> 16) & 1u)) >> 16;
}
__device__ __forceinline__ unsigned pk2(float lo, float hi) {
    return bf16rne(lo) | (bf16rne(hi) << 16);
}

__device__ __forceinline__ void row16f(const float* src, float* p) {
    const float4v* pv = (const float4v*)src;
    float4v a0 = pv[0], a1 = pv[1], a2 = pv[2], a3 = pv[3];
    p[0]=a0.x; p[1]=a0.y; p[2]=a0.z; p[3]=a0.w;
    p[4]=a1.x; p[5]=a1.y; p[6]=a1.z; p[7]=a1.w;
    p[8]=a2.x; p[9]=a2.y; p[10]=a2.z; p[11]=a2.w;
    p[12]=a3.x; p[13]=a3.y; p[14]=a3.z; p[15]=a3.w;
}

// log_softmax of a 16-vector
__device__ __forceinline__ void lsm16(const float* p, float* lp, float* q, float& ne) {
    float m = p[0];
#pragma unroll
    for (int e = 1; e < 16; e++) m = fmaxf(m, p[e]);
    float s = 0.f;
#pragma unroll
    for (int e = 0; e < 16; e++) s += expf(p[e] - m);
    const float ls = logf(s);
    ne = 0.f;
#pragma unroll
    for (int e = 0; e < 16; e++) {
        lp[e] = p[e] - m - ls;
        q[e]  = expf(lp[e]);
        ne   += q[e] * lp[e];
    }
}

// ---------------- convert emb f32 -> bf16; block 0 also zeroes accumulators ----------------
__global__ __launch_bounds__(256) void conv_init(
    const float* __restrict__ src, unsigned short* __restrict__ dst, float* __restrict__ acc)
{
    if (blockIdx.x == 0 && threadIdx.x < ACC_F) acc[threadIdx.x] = 0.f;
    const size_t i = ((size_t)blockIdx.x * 256 + threadIdx.x) * 8;
    float4v a = *(const float4v*)(src + i);
    float4v b = *(const float4v*)(src + i + 4);
    uint4 w = {pk2(a.x,a.y), pk2(a.z,a.w), pk2(b.x,b.y), pk2(b.z,b.w)};
    *(uint4*)(dst + i) = w;
}

// XCD-locality decode: 528 = 66 x 8; ids with equal id%8 walk a clustered order over
// 4-tile row/col groups so each XCD's instantaneous working set is ~3 MB (< 4 MB L2).
__device__ __forceinline__ void decode_pair(int id, int& bi, int& bj) {
    int L = (id & 7) * 66 + (id >> 3);
    int gi = 0, gj = 0;
    for (;;) {
        const int cnt = (gi == gj) ? 10 : 16;
        if (L < cnt) break;
        L -= cnt;
        gj++; if (gj == 8) { gi++; gj = gi; }
    }
    if (gi == gj) {
        int u = 0, c = 4;
        while (L >= c) { L -= c; u++; c--; }
        bi = gi * 4 + u; bj = gj * 4 + u + L;
    } else {
        bi = gi * 4 + (L >> 2); bj = gj * 4 + (L & 3);
    }
}

// ---------------- Kernel B: symmetric Gram GEMM + MFMA-ized masked KL + finalize ----------------
// 512 threads / 8 waves; wave owns a 32x64 quadrant (2x4 16x16 frags).
// K-loop: depth-2 register prefetch (load issued at iter k consumed at k+2) to cover
// the ~600-900cyc L3-miss tail latency that the per-iter barrier exposes (R7 analysis).
// Epilogue: kl matrices computed as K=17 augmented GEMMs via MFMA (same C-layout as Gram).
template<bool PRE>
__global__ __launch_bounds__(512, 4) void gram_kl(
    const float* __restrict__ embf, const unsigned short* __restrict__ embb,
    const float* __restrict__ rp, float* __restrict__ acc,
    unsigned int* __restrict__ out)
{
    __shared__ char smem[32768];
    __shared__ float red[16];
    __shared__ int islast;
    __shared__ float fin[96];
    // K-loop view (first 16 KB):
    __hip_bfloat16* tA = (__hip_bfloat16*)smem;            // [128][32] bf16, chunk-swizzled
    __hip_bfloat16* tB = (__hip_bfloat16*)(smem + 8192);
    // epilogue view (32 KB, same geometry/swizzle): augmented bf16 rows [128][32]
    __hip_bfloat16* eAF = (__hip_bfloat16*)smem;             // I: [lp_i, 1, 0...]
    __hip_bfloat16* eBF = (__hip_bfloat16*)(smem + 8192);    // J: [-q_j, ne_j, 0...]
    __hip_bfloat16* eAR = (__hip_bfloat16*)(smem + 16384);   // I: [q_i, ne_i, 0...]
    __hip_bfloat16* eBR = (__hip_bfloat16*)(smem + 24576);   // J: [-lp_j, 1, 0...]

    int bi, bj;
    decode_pair((int)blockIdx.x, bi, bj);

    const int t = threadIdx.x;
    const int lane = t & 63, wid = t >> 6;           // 8 waves
    const int wi0 = (wid >> 1) * 32, wj0 = (wid & 1) * 64;   // 32x64 quadrant
    const int lrow = lane & 15, quad = lane >> 4;

    // staging: 512 threads cover 128 rows x 4 chunks; 1 chunk per tile each
    const int row = t >> 2, cp = t & 3;
    const int sw  = cp ^ ((row >> 1) & 3);           // XOR bank swizzle
    const int off = row * 32 + sw * 8;

    float4v accf[2][4];
#pragma unroll
    for (int a = 0; a < 2; a++)
#pragma unroll
        for (int b = 0; b < 4; b++) { accf[a][b].x=0.f; accf[a][b].y=0.f; accf[a][b].z=0.f; accf[a][b].w=0.f; }

    // fragment read offsets (swizzle depends only on row); shared by K-loop and epilogue
    int roA[2], roB[4];
#pragma unroll
    for (int f = 0; f < 2; f++) {
        const int ra = wi0 + f * 16 + lrow;
        roA[f] = ra * 32 + (quad ^ ((ra >> 1) & 3)) * 8;
    }
#pragma unroll
    for (int f = 0; f < 4; f++) {
        const int rb = wj0 + f * 16 + lrow;
        roB[f] = rb * 32 + (quad ^ ((rb >> 1) & 3)) * 8;
    }

    if (PRE) {
        const unsigned short* gA = embb + (size_t)(bi * 128) * HDIM + (size_t)row * HDIM + cp * 8;
        const unsigned short* gB = embb + (size_t)(bj * 128) * HDIM + (size_t)row * HDIM + cp * 8;
        // depth-2 pipeline: preload tiles 0 and 1
        uint4 va0 = *(const uint4*)(gA);
        uint4 vb0 = *(const uint4*)(gB);
        uint4 va1 = *(const uint4*)(gA + 32);
        uint4 vb1 = *(const uint4*)(gB + 32);
        for (int kt = 0; kt < HDIM; kt += 64) {
            // phase 0: consume tile kt, prefetch tile kt+64
            __syncthreads();
            *(uint4*)(tA + off) = va0;
            *(uint4*)(tB + off) = vb0;
            __syncthreads();
            {
                const int kn = (kt + 64 < HDIM) ? (kt + 64) : kt;   // uniform clamp
                va0 = *(const uint4*)(gA + kn);
                vb0 = *(const uint4*)(gB + kn);
            }
            {
                short8 a[2], b[4];
#pragma unroll
                for (int f = 0; f < 2; f++) a[f] = *(const short8*)(tA + roA[f]);
#pragma unroll
                for (int f = 0; f < 4; f++) b[f] = *(const short8*)(tB + roB[f]);
#pragma unroll
                for (int fi = 0; fi < 2; fi++)
#pragma unroll
                    for (int fj = 0; fj < 4; fj++)
                        accf[fi][fj] = __builtin_amdgcn_mfma_f32_16x16x32_bf16(
                            a[fi], b[fj], accf[fi][fj], 0, 0, 0);
            }
            // phase 1: consume tile kt+32, prefetch tile kt+96
            __syncthreads();
            *(uint4*)(tA + off) = va1;
            *(uint4*)(tB + off) = vb1;
            __syncthreads();
            {
                const int kn = (kt + 96 < HDIM) ? (kt + 96) : (kt + 32);
                va1 = *(const uint4*)(gA + kn);
                vb1 = *(const uint4*)(gB + kn);
            }
            {
                short8 a[2], b[4];
#pragma unroll
                for (int f = 0; f < 2; f++) a[f] = *(const short8*)(tA + roA[f]);
#pragma unroll
                for (int f = 0; f < 4; f++) b[f] = *(const short8*)(tB + roB[f]);
#pragma unroll
                for (int fi = 0; fi < 2; fi++)
#pragma unroll
                    for (int fj = 0; fj < 4; fj++)
                        accf[fi][fj] = __builtin_amdgcn_mfma_f32_16x16x32_bf16(
                            a[fi], b[fj], accf[fi][fj], 0, 0, 0);
            }
        }
    } else {
        // fallback (ws too small): in-loop f32->bf16 conversion, depth-1
        const float* gA = embf + (size_t)(bi * 128) * HDIM;
        const float* gB = embf + (size_t)(bj * 128) * HDIM;
        float4v a0, a1, b0, b1;
        {
            const float* pa = gA + (size_t)row * HDIM + cp * 8;
            const float* pb = gB + (size_t)row * HDIM + cp * 8;
            a0 = *(const float4v*)pa; a1 = *(const float4v*)(pa + 4);
            b0 = *(const float4v*)pb; b1 = *(const float4v*)(pb + 4);
        }
        for (int kt = 0; kt < HDIM; kt += 32) {
            uint4 wa = {pk2(a0.x,a0.y), pk2(a0.z,a0.w), pk2(a1.x,a1.y), pk2(a1.z,a1.w)};
            uint4 wb = {pk2(b0.x,b0.y), pk2(b0.z,b0.w), pk2(b1.x,b1.y), pk2(b1.z,b1.w)};
            __syncthreads();
            *(uint4*)(tA + off) = wa;
            *(uint4*)(tB + off) = wb;
            __syncthreads();
            const int kn = (kt + 32 < HDIM) ? (kt + 32) : kt;
            const float* pa = gA + (size_t)row * HDIM + kn + cp * 8;
            const float* pb = gB + (size_t)row * HDIM + kn + cp * 8;
            a0 = *(const float4v*)pa; a1 = *(const float4v*)(pa + 4);
            b0 = *(const float4v*)pb; b1 = *(const float4v*)(pb + 4);
            short8 a[2], b[4];
#pragma unroll
            for (int f = 0; f < 2; f++) a[f] = *(const short8*)(tA + roA[f]);
#pragma unroll
            for (int f = 0; f < 4; f++) b[f] = *(const short8*)(tB + roB[f]);
#pragma unroll
            for (int fi = 0; fi < 2; fi++)
#pragma unroll
                for (int fj = 0; fj < 4; fj++)
                    accf[fi][fj] = __builtin_amdgcn_mfma_f32_16x16x32_bf16(
                        a[fi], b[fj], accf[fi][fj], 0, 0, 0);
        }
    }
    __syncthreads();  // K-loop LDS reads done before epilogue overwrites smem

    // ---- epilogue staging: augmented bf16 rows for the KL GEMMs ----
    // F[i][j] = aF_i . bF_j = ne_j - lp_i.q_j   (forward KL)
    // R[i][j] = aR_i . bR_j = ne_i - q_i.lp_j   (reverse KL, off-diag only)
    {
        float p[16], lp[16], q[16], ne;
        const bool iSide = (t < 128);
        if (t < 256) {
            const int rloc = iSide ? t : (t - 128);
            const int grow = (iSide ? bi : bj) * 128 + rloc;
            row16f(rp + (size_t)grow * NE, p);
            lsm16(p, lp, q, ne);
            float r1[16], r2[16], x1, x2;
            if (iSide) {
#pragma unroll
                for (int e = 0; e < 16; e++) { r1[e] = lp[e]; r2[e] = q[e]; }
                x1 = 1.f; x2 = ne;
            } else {
#pragma unroll
                for (int e = 0; e < 16; e++) { r1[e] = -q[e]; r2[e] = -lp[e]; }
                x1 = ne; x2 = 1.f;
            }
            const int s = (rloc >> 1) & 3;
            __hip_bfloat16* d1 = (iSide ? eAF : eBF) + rloc * 32;
            __hip_bfloat16* d2 = (iSide ? eAR : eBR) + rloc * 32;
            uint4 w0 = {pk2(r1[0],r1[1]), pk2(r1[2],r1[3]), pk2(r1[4],r1[5]), pk2(r1[6],r1[7])};
            uint4 w1 = {pk2(r1[8],r1[9]), pk2(r1[10],r1[11]), pk2(r1[12],r1[13]), pk2(r1[14],r1[15])};
            uint4 w2 = {pk2(x1, 0.f), 0u, 0u, 0u};
            uint4 w3 = {0u, 0u, 0u, 0u};
            *(uint4*)(d1 + (0 ^ s) * 8) = w0;
            *(uint4*)(d1 + (1 ^ s) * 8) = w1;
            *(uint4*)(d1 + (2 ^ s) * 8) = w2;
            *(uint4*)(d1 + (3 ^ s) * 8) = w3;
            uint4 v0 = {pk2(r2[0],r2[1]), pk2(r2[2],r2[3]), pk2(r2[4],r2[5]), pk2(r2[6],r2[7])};
            uint4 v1 = {pk2(r2[8],r2[9]), pk2(r2[10],r2[11]), pk2(r2[12],r2[13]), pk2(r2[14],r2[15])};
            uint4 v2 = {pk2(x2, 0.f), 0u, 0u, 0u};
            *(uint4*)(d2 + (0 ^ s) * 8) = v0;
            *(uint4*)(d2 + (1 ^ s) * 8) = v1;
            *(uint4*)(d2 + (2 ^ s) * 8) = v2;
            *(uint4*)(d2 + (3 ^ s) * 8) = w3;
        }
        if (bi == bj && iSide) {   // fold row stats (each row in exactly one diag block's I side)
            float ent = 0.f, eff = 0.f;
#pragma unroll
            for (int e = 0; e < 16; e++) {
                ent += p[e] * logf(p[e] + 1e-8f);
                if (p[e] < 0.1f) eff += p[e];
            }
#pragma unroll
            for (int e = 0; e < 18; e++) {
                float v = (e < 16) ? p[e] : ((e == 16) ? ent : eff);
#pragma unroll
                for (int off2 = 32; off2 > 0; off2 >>= 1) v += __shfl_down(v, off2);
                if (lane == 0) atomicAdd(&acc[e], v);
            }
        }
    }
    __syncthreads();

    // ---- KL GEMMs via MFMA (single K=32 step each, same C layout as accf) ----
    float4v accF[2][4], accR[2][4];
    {
        const float4v z = {0.f, 0.f, 0.f, 0.f};
        short8 af[2], ar[2], bfr[4], brr[4];
#pragma unroll
        for (int f = 0; f < 2; f++) {
            af[f] = *(const short8*)(eAF + roA[f]);
            ar[f] = *(const short8*)(eAR + roA[f]);
        }
#pragma unroll
        for (int f = 0; f < 4; f++) {
            bfr[f] = *(const short8*)(eBF + roB[f]);
            brr[f] = *(const short8*)(eBR + roB[f]);
        }
#pragma unroll
        for (int fi = 0; fi < 2; fi++)
#pragma unroll
            for (int fj = 0; fj < 4; fj++) {
                accF[fi][fj] = __builtin_amdgcn_mfma_f32_16x16x32_bf16(af[fi], bfr[fj], z, 0, 0, 0);
                accR[fi][fj] = __builtin_amdgcn_mfma_f32_16x16x32_bf16(ar[fi], brr[fj], z, 0, 0, 0);
            }
    }

    // ---- mask + accumulate ----
    float klacc = 0.f, cntacc = 0.f;
    const bool offd = (bi != bj);
#pragma unroll
    for (int fi = 0; fi < 2; fi++) {
#pragma unroll
        for (int fj = 0; fj < 4; fj++) {
#pragma unroll
            for (int rg = 0; rg < 4; rg++) {
                const int ig = bi * 128 + wi0 + fi * 16 + quad * 4 + rg;
                const int jg = bj * 128 + wj0 + fj * 16 + lrow;
                const float g = accf[fi][fj][rg];
                if ((g > 0.f) && (ig != jg)) {
                    klacc  += accF[fi][fj][rg];
                    cntacc += 1.f;
                    if (offd) { klacc += accR[fi][fj][rg]; cntacc += 1.f; }
                }
            }
        }
    }

    // block reduce -> striped atomics
#pragma unroll
    for (int off2 = 32; off2 > 0; off2 >>= 1) {
        klacc  += __shfl_down(klacc, off2);
        cntacc += __shfl_down(cntacc, off2);
    }
    if (lane == 0) { red[wid] = klacc; red[8 + wid] = cntacc; }
    __syncthreads();
    if (t == 0) {
        float k = 0.f, c = 0.f;
#pragma unroll
        for (int w = 0; w < 8; w++) { k += red[w]; c += red[8 + w]; }
        atomicAdd(&acc[18 + ((int)blockIdx.x & 31)], k);
        atomicAdd(&acc[50 + ((int)blockIdx.x & 31)], c);
        // release-scoped ticket: wbL2 only -- must NOT invalidate L2 (R5 regression was
        // __threadfence()'s buffer_inv nuking embb from L2 on every block completion)
        const unsigned got = __hip_atomic_fetch_add((unsigned int*)(acc + 82), 1u,
                                                    __ATOMIC_RELEASE, __HIP_MEMORY_SCOPE_AGENT);
        islast = (got == NBLK - 1) ? 1 : 0;
    }
    __syncthreads();

    // ---- last-finished block finalizes ----
    if (islast) {
        if (t == 0)   // acquire pairs with all writers' releases
            (void)__hip_atomic_load((unsigned int*)(acc + 82), __ATOMIC_ACQUIRE,
                                    __HIP_MEMORY_SCOPE_AGENT);
        __syncthreads();
        if (t < 82)   // agent-scope loads read the coherent point
            fin[t] = __hip_atomic_load(&acc[t], __ATOMIC_RELAXED, __HIP_MEMORY_SCOPE_AGENT);
        __syncthreads();
        if (t == 0) {
            float u[16], usum = 0.f;
#pragma unroll
            for (int e = 0; e < 16; e++) { u[e] = fin[e] / (float)BROWS; usum += u[e]; }
            const float mean = usum / 16.f;
            float var = 0.f;
#pragma unroll
            for (int e = 0; e < 16; e++) { float dd = u[e] - mean; var += dd * dd; }
            var /= 15.f;
            const float lb  = var * 256.f;
            const float ent = fin[16] / (float)BROWS;
            const float eff = fin[17] / (float)BROWS;
            float kl = 0.f, cnt = 0.f;
#pragma unroll
            for (int s = 0; s < 32; s++) { kl += fin[18 + s]; cnt += fin[50 + s]; }
            const float cons = (cnt > 0.f) ? (kl / fmaxf(cnt, 1.f)) : 0.f;
            const float total = lb + ent + eff + cons;
            // low16 = exact bf16(total); full word ~ f32(total) (rel err < 2^-9)
            const unsigned fb   = __float_as_uint(total);
            const unsigned hi   = fb >> 16;
            const unsigned mant = fb & 0xFFFFu;
            const unsigned rnd  = (mant > 0x8000u || (mant == 0x8000u && (hi & 1))) ? 1u : 0u;
            out[0] = (fb & 0xFFFF0000u) | ((hi + rnd) & 0xFFFFu);
        }
    }
}

extern "C" void kernel_launch(void* const* d_in, const int* in_sizes, int n_in,
                              void* d_out, int out_size, void* d_ws, size_t ws_size,
                              hipStream_t stream) {
    const float* rp  = (const float*)d_in[0];   // [4096,16]   f32
    const float* emb = (const float*)d_in[1];   // [4096,1024] f32
    float* acc = (float*)d_ws;
    unsigned short* embb = (unsigned short*)((char*)d_ws + ACC_F * sizeof(float));
    (void)in_sizes; (void)n_in; (void)out_size;

    const size_t need = ACC_F * sizeof(float) + (size_t)BROWS * HDIM * 2;
    const bool pre = (ws_size >= need);   // constant across calls -> capture-safe

    if (pre) {
        conv_init<<<(BROWS * HDIM) / (256 * 8), 256, 0, stream>>>(emb, embb, acc);
        gram_kl<true><<<NBLK, 512, 0, stream>>>(emb, embb, rp, acc, (unsigned int*)d_out);
    } else {
        conv_init<<<1, 256, 0, stream>>>(emb, embb, acc);  // still zeroes acc (block 0)
        gram_kl<false><<<NBLK, 512, 0, stream>>>(emb, (const unsigned short*)nullptr, rp, acc,
                                                 (unsigned int*)d_out);
    }
}